// Round 14
// baseline (196.663 us; speedup 1.0000x reference)
//
#include <hip/hip_runtime.h>
#include <hip/hip_bf16.h>

typedef unsigned short u16;
typedef __attribute__((ext_vector_type(8))) short bf16x8;
typedef __attribute__((ext_vector_type(4))) float f32x4;
typedef __attribute__((ext_vector_type(8))) unsigned short u16x8;
typedef __attribute__((ext_vector_type(4))) unsigned short u16x4;

#define N_POS 4096
#define HEADS 8
#define DHEAD 64
#define CIN   256
#define INNER 512
#define NSPLIT 2
#define JCHUNK (N_POS / NSPLIT)

__device__ __forceinline__ u16 f2bf(float f) {
    union { float f; unsigned int u; } v; v.f = f;
    unsigned int u = v.u + 0x7FFFu + ((v.u >> 16) & 1u);   // RNE
    return (u16)(u >> 16);
}

__device__ __forceinline__ float bf2f(u16 h) {
    union { float f; unsigned int u; } v; v.u = ((unsigned int)h) << 16;
    return v.f;
}

__device__ __forceinline__ unsigned int pkbf2(float lo, float hi) {
    union { __hip_bfloat162 b; unsigned int u; } cv;
    cv.b = __float22bfloat162_rn(make_float2(lo, hi));
    return cv.u;
}

// ---------------- K1: QKV projection, x read ONCE per sel -------------------
// Traffic-driven rebuild.  Old geometry (64o tiles, 24 by-blocks) re-read the
// 8.4 MB fp32 x 24x = 201 MB, all L3-served (x >> 4MB per-XCD L2).  New
// geometry: block = 64n x ALL 512o of one sel (Q/K/V), 512 threads, wave=head.
// x traffic drops to 3 x 8.4 = 25 MB; w_qkv (1.57 MB, L2-RESIDENT on every
// XCD) is re-read instead (+150 MB at 34 TB/s aggregate L2 ~ 5 us).
// r13 BUGFIX: A-stage now converts ALL 32 columns per w-row (one thread owns
// a full row; previous version staged only cols 0..15 -> NaN from quad>=2
// fragments reading uninitialized LDS).
// For V (sel==2) MFMA operands are SWAPPED (A/B frags share lane layout) ->
// transposed C -> coalesced u16x4 V^T stores.  by==3 (bx<8): w_out -> bf16.
__global__ __launch_bounds__(512, 2) void k1_qkv(const float* __restrict__ x,
                                                 const float* __restrict__ w_qkv,
                                                 const float* __restrict__ w_out,
                                                 u16* __restrict__ q_ws,
                                                 u16* __restrict__ k_ws,
                                                 u16* __restrict__ vt_ws,
                                                 u16* __restrict__ wo) {
    __shared__ u16 Alds[512 * 40];       // w rows of this sel: 512o x 32c
    __shared__ u16 Blds[64 * 40];        // x tile: 64n x 32c
    int tid = threadIdx.x;
    int by  = blockIdx.y;                // 0..2 = sel (Q/K/V); 3 = wo-convert
    int b   = blockIdx.z;

    if (by == 3) {                       // w_out fp32 -> bf16 (131072 elems)
        if (blockIdx.x >= 8) return;
        size_t base = ((size_t)((b * 8 + blockIdx.x) * 512 + tid)) * 16;
        const float* src = w_out + base;
        union { unsigned int u[4]; u16x8 v; } o0, o1;
        for (int j = 0; j < 4; ++j) o0.u[j] = pkbf2(src[2 * j],     src[2 * j + 1]);
        for (int j = 0; j < 4; ++j) o1.u[j] = pkbf2(src[8 + 2 * j], src[9 + 2 * j]);
        *(u16x8*)(wo + base)     = o0.v;
        *(u16x8*)(wo + base + 8) = o1.v;
        return;
    }

    int n0  = blockIdx.x * 64;           // 64 n-tiles
    int sel = by;
    int wv = tid >> 6, l = tid & 63, quad = l >> 4, l15 = l & 15;

    const float* xb = x + (size_t)b * CIN * N_POS + n0 + (tid & 63);
    int xc = (tid >> 6) * 4;             // c-group this thread stages

    f32x4 acc[4][4] = {};                // [ot][nt] : o = wv*64+ot*16, n = nt*16
    for (int c0 = 0; c0 < CIN; c0 += 32) {
        {   // A-stage: w_qkv row sel*512+tid, ALL 32 cols c0..c0+31
            const float* wqp = w_qkv + (size_t)(sel * 512 + tid) * CIN + c0;
            union { unsigned int u[4]; u16x8 v; } a0, a1, a2, a3;
            for (int j = 0; j < 4; ++j) a0.u[j] = pkbf2(wqp[2 * j],      wqp[2 * j + 1]);
            for (int j = 0; j < 4; ++j) a1.u[j] = pkbf2(wqp[8 + 2 * j],  wqp[9 + 2 * j]);
            for (int j = 0; j < 4; ++j) a2.u[j] = pkbf2(wqp[16 + 2 * j], wqp[17 + 2 * j]);
            for (int j = 0; j < 4; ++j) a3.u[j] = pkbf2(wqp[24 + 2 * j], wqp[25 + 2 * j]);
            *(u16x8*)&Alds[tid * 40]      = a0.v;
            *(u16x8*)&Alds[tid * 40 + 8]  = a1.v;
            *(u16x8*)&Alds[tid * 40 + 16] = a2.v;
            *(u16x8*)&Alds[tid * 40 + 24] = a3.v;
        }
        {   // B-stage: x transpose pattern, 4 c-rows per thread, coalesced n
            u16x4 bv;
            for (int i = 0; i < 4; ++i)
                bv[i] = f2bf(xb[(size_t)(c0 + xc + i) * N_POS]);
            *(u16x4*)&Blds[(tid & 63) * 40 + xc] = bv;
        }
        __syncthreads();
        for (int ot = 0; ot < 4; ++ot) {
            bf16x8 af = *(const bf16x8*)&Alds[(wv * 64 + ot * 16 + l15) * 40 + quad * 8];
            if (sel < 2) {
                for (int nt = 0; nt < 4; ++nt) {
                    bf16x8 bfrag = *(const bf16x8*)&Blds[(nt * 16 + l15) * 40 + quad * 8];
                    acc[ot][nt] = __builtin_amdgcn_mfma_f32_16x16x32_bf16(af, bfrag, acc[ot][nt], 0, 0, 0);
                }
            } else {
                for (int nt = 0; nt < 4; ++nt) {
                    bf16x8 bfrag = *(const bf16x8*)&Blds[(nt * 16 + l15) * 40 + quad * 8];
                    acc[ot][nt] = __builtin_amdgcn_mfma_f32_16x16x32_bf16(bfrag, af, acc[ot][nt], 0, 0, 0);
                }
            }
        }
        __syncthreads();
    }
    const float QSCALE = 0.125f * 1.44269504088896f;
    int bh = b * HEADS + wv;             // wave = head
    if (sel < 2) {
        float sc = (sel == 0) ? QSCALE : 1.0f;
        u16* base = (sel == 0) ? q_ws : k_ws;
        for (int ot = 0; ot < 4; ++ot) {
            int dbase = ot * 16 + quad * 4;      // d = C m-rows
            for (int nt = 0; nt < 4; ++nt) {
                int n = n0 + nt * 16 + l15;      // n = C cols
                u16x4 pk;
                for (int r = 0; r < 4; ++r) pk[r] = f2bf(acc[ot][nt][r] * sc);
                *(u16x4*)&base[((size_t)bh * N_POS + n) * DHEAD + dbase] = pk;
            }
        }
    } else {
        for (int ot = 0; ot < 4; ++ot) {
            int dloc = ot * 16 + l15;            // d = C cols (swapped)
            for (int nt = 0; nt < 4; ++nt) {
                u16x4 pk;                        // C rows = 4 consecutive n
                for (int r = 0; r < 4; ++r) pk[r] = f2bf(acc[ot][nt][r]);
                *(u16x4*)&vt_ws[((size_t)bh * DHEAD + dloc) * N_POS
                                + n0 + nt * 16 + quad * 4] = pk;
            }
        }
    }
}

// ---------------- K2: flash attention, seam-interleaved (r12, 87.3us) -------
// dbuf + lsum-in-MFMA (ones-rows) + seam-interleaved j-step.  UNCHANGED from
// r12 -- control kernel: counters must not move.
__global__ __launch_bounds__(256, 2) void k2_attn(const u16* __restrict__ q_ws,
                                                  const u16* __restrict__ k_ws,
                                                  const u16* __restrict__ vt_ws,
                                                  u16* __restrict__ op_ws,
                                                  float* __restrict__ lw_ws) {
    __shared__ u16 Klds[2][64 * 72];     // row slot sigma(j), 64 d-values
    __shared__ u16 Vlds[2][80 * 72];     // V^T: [d][j]; rows 64..79 constant
    int tid = threadIdx.x;
    int v   = blockIdx.x + (blockIdx.y << 4) + (blockIdx.z << 8);
    int slot = v & 7, idx = v >> 3;
    int bh   = slot * 2 + (idx & 1);
    int q0   = ((idx >> 1) & 15) * 256;
    int half = idx >> 5;
    int jbase = half * JCHUNK;
    int wv = tid >> 6, l = tid & 63, quad = l >> 4, l15 = l & 15;
    int srow = tid >> 2, sseg = tid & 3;
    // sigma(j) = p*32 + a*16 + q'*4 + r  for j = p q1 q0 a r1 r0 (bits 5..0)
    int srowp = (srow & 0x23) | ((srow & 4) << 2) | ((srow & 0x18) >> 1);
    int kofs = srowp * 72 + sseg * 16;
    int vofs = srow * 72 + sseg * 16;

    // Q fragments as MFMA B operand (n=l15 -> q-row i, k=quad*8+jj = d)
    const u16* qp = q_ws + ((size_t)(bh * N_POS + q0 + wv * 64 + l15)) * DHEAD + quad * 8;
    bf16x8 bq[4][2];
    for (int it = 0; it < 4; ++it) {
        bq[it][0] = *(const bf16x8*)(qp + (size_t)it * 16 * DHEAD);
        bq[it][1] = *(const bf16x8*)(qp + (size_t)it * 16 * DHEAD + 32);
    }

    f32x4 Oacc[4][5] = {};               // [it][dt]: dt<4 = O^T; dt=4 row0 = lsum

    const u16* kp = k_ws + ((size_t)(bh * N_POS + srow)) * DHEAD + sseg * 16;
    const u16* vp = vt_ws + ((size_t)(bh * DHEAD + srow)) * N_POS + sseg * 16;

    // constant ones/zeros rows 64..79 of V^T (both buffers), written once
    {
        int r2 = tid >> 4, c4 = (tid & 15) * 4;
        u16 one = (r2 == 0) ? (u16)0x3F80 : (u16)0;   // bf16(1.0) on row 64
        u16x4 cv = {one, one, one, one};
        *(u16x4*)&Vlds[0][(64 + r2) * 72 + c4] = cv;
        *(u16x4*)&Vlds[1][(64 + r2) * 72 + c4] = cv;
    }

    // prologue: tile 0 -> regs -> buf0; prefetch tile 1 -> regs; barrier
    u16x8 pf0 = *(const u16x8*)(kp + (size_t)jbase * DHEAD);
    u16x8 pf1 = *(const u16x8*)(kp + (size_t)jbase * DHEAD + 8);
    u16x8 pf2 = *(const u16x8*)(vp + jbase);
    u16x8 pf3 = *(const u16x8*)(vp + jbase + 8);
    *(u16x8*)&Klds[0][kofs]     = pf0;
    *(u16x8*)&Klds[0][kofs + 8] = pf1;
    *(u16x8*)&Vlds[0][vofs]     = pf2;
    *(u16x8*)&Vlds[0][vofs + 8] = pf3;
    {
        const u16* kpj = kp + (size_t)(jbase + 64) * DHEAD;
        pf0 = *(const u16x8*)kpj;
        pf1 = *(const u16x8*)(kpj + 8);
        pf2 = *(const u16x8*)(vp + jbase + 64);
        pf3 = *(const u16x8*)(vp + jbase + 72);
    }
    __syncthreads();

    union PF { unsigned int u[4]; bf16x8 v; };
    int cur = 0;
    for (int j0 = jbase; j0 < jbase + JCHUNK; j0 += 64) {
        // write tile k+1 into the other buffer (overlaps compute below)
        if (j0 + 64 < jbase + JCHUNK) {
            *(u16x8*)&Klds[cur ^ 1][kofs]     = pf0;
            *(u16x8*)&Klds[cur ^ 1][kofs + 8] = pf1;
            *(u16x8*)&Vlds[cur ^ 1][vofs]     = pf2;
            *(u16x8*)&Vlds[cur ^ 1][vofs + 8] = pf3;
        }

        PF pfr[4][2];                    // [it][p] : K=32 B-fragment in place
        f32x4 z0[4], z1[4];

        auto QK = [&](f32x4* z, int p, int a) {
            const u16* kb = &Klds[cur][((2 * p + a) * 16 + l15) * 72 + quad * 8];
            bf16x8 kf0 = *(const bf16x8*)kb;
            bf16x8 kf1 = *(const bf16x8*)(kb + 32);
            __builtin_amdgcn_s_setprio(1);
            #pragma unroll
            for (int it = 0; it < 4; ++it) {
                f32x4 t = {};
                t = __builtin_amdgcn_mfma_f32_16x16x32_bf16(kf0, bq[it][0], t, 0, 0, 0);
                t = __builtin_amdgcn_mfma_f32_16x16x32_bf16(kf1, bq[it][1], t, 0, 0, 0);
                z[it] = t;
            }
            __builtin_amdgcn_s_setprio(0);
        };
        auto EXPPACK = [&](f32x4* z, int p, int a) {
            #pragma unroll
            for (int it = 0; it < 4; ++it) {
                float e0 = __builtin_amdgcn_exp2f(z[it][0]);
                float e1 = __builtin_amdgcn_exp2f(z[it][1]);
                float e2 = __builtin_amdgcn_exp2f(z[it][2]);
                float e3 = __builtin_amdgcn_exp2f(z[it][3]);
                pfr[it][p].u[2 * a]     = pkbf2(e0, e1);
                pfr[it][p].u[2 * a + 1] = pkbf2(e2, e3);
            }
        };
        auto PV = [&](int p, int dt_lo, int dt_hi) {
            __builtin_amdgcn_s_setprio(1);
            for (int dt = dt_lo; dt < dt_hi; ++dt) {
                bf16x8 vf = *(const bf16x8*)&Vlds[cur][(dt * 16 + l15) * 72 + p * 32 + quad * 8];
                #pragma unroll
                for (int it = 0; it < 4; ++it)
                    Oacc[it][dt] = __builtin_amdgcn_mfma_f32_16x16x32_bf16(vf, pfr[it][p].v, Oacc[it][dt], 0, 0, 0);
            }
            __builtin_amdgcn_s_setprio(0);
        };

        // seam-interleaved schedule
        QK(z0, 0, 0);
        QK(z1, 0, 1);                    // covers z0 latency
        EXPPACK(z0, 0, 0);
        EXPPACK(z1, 0, 1);               // pfr[*][0] now complete
        QK(z0, 1, 0);
        PV(0, 0, 2);                     // covers z0(p1a0) latency
        EXPPACK(z0, 1, 0);
        QK(z1, 1, 1);
        PV(0, 2, 5);                     // covers z1(p1a1) latency
        EXPPACK(z1, 1, 1);               // pfr[*][1] now complete
        PV(1, 0, 5);

        // prefetch tile k+2 into regs (overlaps next iter's compute issue)
        if (j0 + 128 < jbase + JCHUNK) {
            const u16* kpj = kp + (size_t)(j0 + 128) * DHEAD;
            pf0 = *(const u16x8*)kpj;
            pf1 = *(const u16x8*)(kpj + 8);
            pf2 = *(const u16x8*)(vp + j0 + 128);
            pf3 = *(const u16x8*)(vp + j0 + 136);
        }
        __syncthreads();                 // ONE barrier per j-step
        cur ^= 1;
    }

    // epilogue: store unnormalized bf16 partial + lsum partial (from MFMA)
    int b = bh >> 3, h = bh & 7;
    u16* opb = op_ws + (size_t)half * 2 * N_POS * INNER;
    float* lwb = lw_ws + (size_t)half * 2 * HEADS * N_POS;
    for (int it = 0; it < 4; ++it) {
        int n = q0 + wv * 64 + it * 16 + l15;
        if (quad == 0) lwb[(size_t)bh * N_POS + n] = Oacc[it][4][0];
        u16* dst = opb + ((size_t)(b * N_POS + n)) * INNER + h * DHEAD;
        for (int dt = 0; dt < 4; ++dt) {
            u16x4 pk;
            for (int r = 0; r < 4; ++r) pk[r] = f2bf(Oacc[it][dt][r]);
            *(u16x4*)&dst[dt * 16 + quad * 4] = pk;
        }
    }
}

// ---------------- K3: combine-once + out-proj + bias (r9-r12-verified) ------
// Block = 16 n-rows x ALL 256 c, 512 threads, grid 512 = 2/CU.  Phase 1: all
// 512 threads combine partials into LDS once.  Phase 2: MFMA loop with
// double-buffered A staging, one barrier per step.  UNCHANGED.
__global__ __launch_bounds__(512) void k3_out(const u16* __restrict__ wo,
                                              const float* __restrict__ b_out,
                                              const u16* __restrict__ op_ws,
                                              const float* __restrict__ lw_ws,
                                              float* __restrict__ out) {
    __shared__ u16 Alds[2][256 * 36];    // [buf][c-row][32 i + 4 pad]
    __shared__ u16 Blds[16 * 520];       // [n-row][512 i + 8 pad]
    int tid = threadIdx.x;
    int n0 = blockIdx.x * 16;
    int b  = blockIdx.y;
    int wv = tid >> 6, l = tid & 63, quad = l >> 4, l15 = l & 15;

    // phase 1: combine 2 bf16 partials -> normalized bf16 B tile in LDS
    {
        int i8 = tid & 63;               // i-chunk of 8 (i = i8*8)
        int h  = i8 >> 3;
        for (int p = 0; p < 2; ++p) {
            int nl = p * 8 + (tid >> 6);
            int n = n0 + nl;
            size_t lidx = ((size_t)(b * HEADS + h)) * N_POS + n;
            float ls = lw_ws[lidx] + lw_ws[(size_t)2 * HEADS * N_POS + lidx];
            float inv = 1.0f / ls;
            size_t oidx = ((size_t)(b * N_POS + n)) * INNER + i8 * 8;
            u16x8 pv0 = *(const u16x8*)(op_ws + oidx);
            u16x8 pv1 = *(const u16x8*)(op_ws + (size_t)2 * N_POS * INNER + oidx);
            u16x8 vv;
            for (int k = 0; k < 8; ++k)
                vv[k] = f2bf((bf2f(pv0[k]) + bf2f(pv1[k])) * inv);
            *(u16x8*)&Blds[nl * 520 + i8 * 8] = vv;
        }
    }
    // stage A for step 0
    {
        int row = tid >> 1, seg = tid & 1;
        const u16* src = wo + (size_t)row * INNER + seg * 16;
        *(u16x8*)&Alds[0][row * 36 + seg * 16]     = *(const u16x8*)src;
        *(u16x8*)&Alds[0][row * 36 + seg * 16 + 8] = *(const u16x8*)(src + 8);
    }
    __syncthreads();

    f32x4 acc[2] = {};                   // [ac] : c = wv*32 + ac*16 + quad*4+r
    int cur = 0;
    for (int s = 0; s < 16; ++s) {
        if (s + 1 < 16) {                // prefetch next A tile (other buffer)
            int row = tid >> 1, seg = tid & 1;
            const u16* src = wo + (size_t)row * INNER + (s + 1) * 32 + seg * 16;
            *(u16x8*)&Alds[cur ^ 1][row * 36 + seg * 16]     = *(const u16x8*)src;
            *(u16x8*)&Alds[cur ^ 1][row * 36 + seg * 16 + 8] = *(const u16x8*)(src + 8);
        }
        for (int ac = 0; ac < 2; ++ac) {
            bf16x8 af = *(const bf16x8*)&Alds[cur][(wv * 32 + ac * 16 + l15) * 36 + quad * 8];
            bf16x8 bfrag = *(const bf16x8*)&Blds[l15 * 520 + s * 32 + quad * 8];
            acc[ac] = __builtin_amdgcn_mfma_f32_16x16x32_bf16(af, bfrag, acc[ac], 0, 0, 0);
        }
        __syncthreads();                 // one barrier per step
        cur ^= 1;
    }
    for (int ac = 0; ac < 2; ++ac)
        for (int r = 0; r < 4; ++r) {
            int c = wv * 32 + ac * 16 + quad * 4 + r;
            out[((size_t)(b * CIN + c)) * N_POS + n0 + l15] = acc[ac][r] + b_out[c];
        }
}

extern "C" void kernel_launch(void* const* d_in, const int* in_sizes, int n_in,
                              void* d_out, int out_size, void* d_ws, size_t ws_size,
                              hipStream_t stream) {
    const float* x     = (const float*)d_in[0];
    const float* w_qkv = (const float*)d_in[1];
    const float* w_out = (const float*)d_in[2];
    const float* b_out = (const float*)d_in[3];
    float* out = (float*)d_out;

    u16* ws    = (u16*)d_ws;
    u16* q_ws  = ws;                                         // 2*8*4096*64 bf16
    u16* k_ws  = q_ws + (size_t)2 * HEADS * N_POS * DHEAD;
    u16* vt_ws = k_ws + (size_t)2 * HEADS * N_POS * DHEAD;
    u16* wo_bf = vt_ws + (size_t)2 * HEADS * N_POS * DHEAD;  // 256*512 bf16
    u16* op_ws = wo_bf + (size_t)CIN * INNER;                // NSPLIT*2*4096*512 bf16
    float* lw_ws = (float*)(op_ws + (size_t)NSPLIT * 2 * N_POS * INNER); // f32

    hipLaunchKernelGGL(k1_qkv, dim3(64, 4, 2), dim3(512), 0, stream,
                       x, w_qkv, w_out, q_ws, k_ws, vt_ws, wo_bf);
    hipLaunchKernelGGL(k2_attn, dim3(16, 16, NSPLIT), dim3(256), 0, stream,
                       q_ws, k_ws, vt_ws, op_ws, lw_ws);
    hipLaunchKernelGGL(k3_out, dim3(256, 2), dim3(512), 0, stream,
                       wo_bf, b_out, op_ws, lw_ws, out);
}

// Round 15
// 175.614 us; speedup vs baseline: 1.1199x; 1.1199x over previous
//
#include <hip/hip_runtime.h>
#include <hip/hip_bf16.h>

typedef unsigned short u16;
typedef __attribute__((ext_vector_type(8))) short bf16x8;
typedef __attribute__((ext_vector_type(4))) float f32x4;
typedef __attribute__((ext_vector_type(8))) unsigned short u16x8;
typedef __attribute__((ext_vector_type(4))) unsigned short u16x4;

#define N_POS 4096
#define HEADS 8
#define DHEAD 64
#define CIN   256
#define INNER 512
#define NSPLIT 2
#define JCHUNK (N_POS / NSPLIT)

__device__ __forceinline__ u16 f2bf(float f) {
    union { float f; unsigned int u; } v; v.f = f;
    unsigned int u = v.u + 0x7FFFu + ((v.u >> 16) & 1u);   // RNE
    return (u16)(u >> 16);
}

__device__ __forceinline__ float bf2f(u16 h) {
    union { float f; unsigned int u; } v; v.u = ((unsigned int)h) << 16;
    return v.f;
}

__device__ __forceinline__ unsigned int pkbf2(float lo, float hi) {
    union { __hip_bfloat162 b; unsigned int u; } cv;
    cv.b = __float22bfloat162_rn(make_float2(lo, hi));
    return cv.u;
}

// ---------------- K1: FUSED prep + QKV projection (r10-r12-verified) --------
// REVERT to r12: the r13/r14 "x-once" geometry was falsified (+22 us — w
// re-read put 256 MB of L2 traffic + 16 pkbf2/thread/step on the staging
// critical path; the old L3-served x re-reads were already hidden under the
// fatter compute phase).  B-stage reads x fp32 directly (strided-coalesced
// transpose) and converts in staging.  A-stage reads w_qkv fp32 + converts.
// by==24 blocks convert w_out -> bf16 for k3.  64o x 256n tiles, 16
// MFMAs/step.  For V (sel==2) MFMA operands are SWAPPED -> transposed C ->
// coalesced u16x4 V^T stores.
__global__ __launch_bounds__(256, 2) void k1_qkv(const float* __restrict__ x,
                                                 const float* __restrict__ w_qkv,
                                                 const float* __restrict__ w_out,
                                                 u16* __restrict__ q_ws,
                                                 u16* __restrict__ k_ws,
                                                 u16* __restrict__ vt_ws,
                                                 u16* __restrict__ wo) {
    __shared__ u16 Alds[64 * 40];
    __shared__ u16 Blds[256 * 40];
    int tid = threadIdx.x;
    int by  = blockIdx.y;           // 0..23 QKV : sel = by/8, h = by%8 ; 24 = wo-convert
    int b   = blockIdx.z;

    if (by == 24) {                 // w_out fp32 -> bf16 (131072 elems / 8192 thr)
        size_t base = ((size_t)((b * 16 + blockIdx.x) * 256 + tid)) * 16;
        const float* src = w_out + base;
        union { unsigned int u[4]; u16x8 v; } o0, o1;
        for (int j = 0; j < 4; ++j) o0.u[j] = pkbf2(src[2 * j],     src[2 * j + 1]);
        for (int j = 0; j < 4; ++j) o1.u[j] = pkbf2(src[8 + 2 * j], src[9 + 2 * j]);
        *(u16x8*)(wo + base)     = o0.v;
        *(u16x8*)(wo + base + 8) = o1.v;
        return;
    }

    int n0  = blockIdx.x * 256;     // 16 x-blocks
    int o0  = by * 64;
    int sel = by >> 3;
    int h   = by & 7;
    int wv = tid >> 6, l = tid & 63, quad = l >> 4, l15 = l & 15;
    int srow = tid >> 2, sseg = tid & 3;

    const float* xb = x + (size_t)b * CIN * N_POS + n0 + tid;

    f32x4 acc[16] = {};
    for (int c0 = 0; c0 < CIN; c0 += 32) {
        {   // A-stage: w_qkv fp32 -> bf16 -> LDS (8 elems/thread)
            const float* wqp = w_qkv + (size_t)(o0 + srow) * CIN + c0 + sseg * 8;
            union { unsigned int u[4]; u16x8 v; } av;
            for (int j = 0; j < 4; ++j) av.u[j] = pkbf2(wqp[2 * j], wqp[2 * j + 1]);
            *(u16x8*)&Alds[srow * 40 + sseg * 8] = av.v;
        }
        {   // B-stage: x fp32 strided (transpose pattern) -> bf16 -> LDS
            union { unsigned int u[16]; } tmp;
            #pragma unroll
            for (int j = 0; j < 16; ++j)
                tmp.u[j] = pkbf2(xb[(size_t)(c0 + 2 * j) * N_POS],
                                 xb[(size_t)(c0 + 2 * j + 1) * N_POS]);
            u16* bd = &Blds[tid * 40];
            *(u16x8*)(bd)      = *(u16x8*)&tmp.u[0];
            *(u16x8*)(bd + 8)  = *(u16x8*)&tmp.u[4];
            *(u16x8*)(bd + 16) = *(u16x8*)&tmp.u[8];
            *(u16x8*)(bd + 24) = *(u16x8*)&tmp.u[12];
        }
        __syncthreads();
        bf16x8 af = *(const bf16x8*)&Alds[(wv * 16 + l15) * 40 + quad * 8];
        if (sel < 2) {
            for (int nt = 0; nt < 16; ++nt) {
                bf16x8 bfrag = *(const bf16x8*)&Blds[(nt * 16 + l15) * 40 + quad * 8];
                acc[nt] = __builtin_amdgcn_mfma_f32_16x16x32_bf16(af, bfrag, acc[nt], 0, 0, 0);
            }
        } else {
            for (int nt = 0; nt < 16; ++nt) {
                bf16x8 bfrag = *(const bf16x8*)&Blds[(nt * 16 + l15) * 40 + quad * 8];
                acc[nt] = __builtin_amdgcn_mfma_f32_16x16x32_bf16(bfrag, af, acc[nt], 0, 0, 0);
            }
        }
        __syncthreads();
    }
    const float QSCALE = 0.125f * 1.44269504088896f;
    int bh = b * HEADS + h;
    if (sel < 2) {
        float sc = (sel == 0) ? QSCALE : 1.0f;
        u16* base = (sel == 0) ? q_ws : k_ws;
        int dbase = wv * 16 + quad * 4;
        for (int nt = 0; nt < 16; ++nt) {
            int n = n0 + nt * 16 + l15;
            u16x4 pk;
            for (int r = 0; r < 4; ++r) pk[r] = f2bf(acc[nt][r] * sc);
            *(u16x4*)&base[((size_t)bh * N_POS + n) * DHEAD + dbase] = pk;
        }
    } else {
        int dloc = wv * 16 + l15;            // C col = o-local = d
        for (int nt = 0; nt < 16; ++nt) {
            u16x4 pk;                        // C rows = 4 consecutive n
            for (int r = 0; r < 4; ++r) pk[r] = f2bf(acc[nt][r]);
            *(u16x4*)&vt_ws[((size_t)bh * DHEAD + dloc) * N_POS
                            + n0 + nt * 16 + quad * 4] = pk;
        }
    }
}

// ---------------- K2: flash attention, seam-interleaved (r12, 87.3us) -------
// dbuf + lsum-in-MFMA (ones-rows) + seam-interleaved j-step.  UNCHANGED from
// r12 -- the measured floor of this structure.
__global__ __launch_bounds__(256, 2) void k2_attn(const u16* __restrict__ q_ws,
                                                  const u16* __restrict__ k_ws,
                                                  const u16* __restrict__ vt_ws,
                                                  u16* __restrict__ op_ws,
                                                  float* __restrict__ lw_ws) {
    __shared__ u16 Klds[2][64 * 72];     // row slot sigma(j), 64 d-values
    __shared__ u16 Vlds[2][80 * 72];     // V^T: [d][j]; rows 64..79 constant
    int tid = threadIdx.x;
    int v   = blockIdx.x + (blockIdx.y << 4) + (blockIdx.z << 8);
    int slot = v & 7, idx = v >> 3;
    int bh   = slot * 2 + (idx & 1);
    int q0   = ((idx >> 1) & 15) * 256;
    int half = idx >> 5;
    int jbase = half * JCHUNK;
    int wv = tid >> 6, l = tid & 63, quad = l >> 4, l15 = l & 15;
    int srow = tid >> 2, sseg = tid & 3;
    // sigma(j) = p*32 + a*16 + q'*4 + r  for j = p q1 q0 a r1 r0 (bits 5..0)
    int srowp = (srow & 0x23) | ((srow & 4) << 2) | ((srow & 0x18) >> 1);
    int kofs = srowp * 72 + sseg * 16;
    int vofs = srow * 72 + sseg * 16;

    // Q fragments as MFMA B operand (n=l15 -> q-row i, k=quad*8+jj = d)
    const u16* qp = q_ws + ((size_t)(bh * N_POS + q0 + wv * 64 + l15)) * DHEAD + quad * 8;
    bf16x8 bq[4][2];
    for (int it = 0; it < 4; ++it) {
        bq[it][0] = *(const bf16x8*)(qp + (size_t)it * 16 * DHEAD);
        bq[it][1] = *(const bf16x8*)(qp + (size_t)it * 16 * DHEAD + 32);
    }

    f32x4 Oacc[4][5] = {};               // [it][dt]: dt<4 = O^T; dt=4 row0 = lsum

    const u16* kp = k_ws + ((size_t)(bh * N_POS + srow)) * DHEAD + sseg * 16;
    const u16* vp = vt_ws + ((size_t)(bh * DHEAD + srow)) * N_POS + sseg * 16;

    // constant ones/zeros rows 64..79 of V^T (both buffers), written once
    {
        int r2 = tid >> 4, c4 = (tid & 15) * 4;
        u16 one = (r2 == 0) ? (u16)0x3F80 : (u16)0;   // bf16(1.0) on row 64
        u16x4 cv = {one, one, one, one};
        *(u16x4*)&Vlds[0][(64 + r2) * 72 + c4] = cv;
        *(u16x4*)&Vlds[1][(64 + r2) * 72 + c4] = cv;
    }

    // prologue: tile 0 -> regs -> buf0; prefetch tile 1 -> regs; barrier
    u16x8 pf0 = *(const u16x8*)(kp + (size_t)jbase * DHEAD);
    u16x8 pf1 = *(const u16x8*)(kp + (size_t)jbase * DHEAD + 8);
    u16x8 pf2 = *(const u16x8*)(vp + jbase);
    u16x8 pf3 = *(const u16x8*)(vp + jbase + 8);
    *(u16x8*)&Klds[0][kofs]     = pf0;
    *(u16x8*)&Klds[0][kofs + 8] = pf1;
    *(u16x8*)&Vlds[0][vofs]     = pf2;
    *(u16x8*)&Vlds[0][vofs + 8] = pf3;
    {
        const u16* kpj = kp + (size_t)(jbase + 64) * DHEAD;
        pf0 = *(const u16x8*)kpj;
        pf1 = *(const u16x8*)(kpj + 8);
        pf2 = *(const u16x8*)(vp + jbase + 64);
        pf3 = *(const u16x8*)(vp + jbase + 72);
    }
    __syncthreads();

    union PF { unsigned int u[4]; bf16x8 v; };
    int cur = 0;
    for (int j0 = jbase; j0 < jbase + JCHUNK; j0 += 64) {
        // write tile k+1 into the other buffer (overlaps compute below)
        if (j0 + 64 < jbase + JCHUNK) {
            *(u16x8*)&Klds[cur ^ 1][kofs]     = pf0;
            *(u16x8*)&Klds[cur ^ 1][kofs + 8] = pf1;
            *(u16x8*)&Vlds[cur ^ 1][vofs]     = pf2;
            *(u16x8*)&Vlds[cur ^ 1][vofs + 8] = pf3;
        }

        PF pfr[4][2];                    // [it][p] : K=32 B-fragment in place
        f32x4 z0[4], z1[4];

        auto QK = [&](f32x4* z, int p, int a) {
            const u16* kb = &Klds[cur][((2 * p + a) * 16 + l15) * 72 + quad * 8];
            bf16x8 kf0 = *(const bf16x8*)kb;
            bf16x8 kf1 = *(const bf16x8*)(kb + 32);
            __builtin_amdgcn_s_setprio(1);
            #pragma unroll
            for (int it = 0; it < 4; ++it) {
                f32x4 t = {};
                t = __builtin_amdgcn_mfma_f32_16x16x32_bf16(kf0, bq[it][0], t, 0, 0, 0);
                t = __builtin_amdgcn_mfma_f32_16x16x32_bf16(kf1, bq[it][1], t, 0, 0, 0);
                z[it] = t;
            }
            __builtin_amdgcn_s_setprio(0);
        };
        auto EXPPACK = [&](f32x4* z, int p, int a) {
            #pragma unroll
            for (int it = 0; it < 4; ++it) {
                float e0 = __builtin_amdgcn_exp2f(z[it][0]);
                float e1 = __builtin_amdgcn_exp2f(z[it][1]);
                float e2 = __builtin_amdgcn_exp2f(z[it][2]);
                float e3 = __builtin_amdgcn_exp2f(z[it][3]);
                pfr[it][p].u[2 * a]     = pkbf2(e0, e1);
                pfr[it][p].u[2 * a + 1] = pkbf2(e2, e3);
            }
        };
        auto PV = [&](int p, int dt_lo, int dt_hi) {
            __builtin_amdgcn_s_setprio(1);
            for (int dt = dt_lo; dt < dt_hi; ++dt) {
                bf16x8 vf = *(const bf16x8*)&Vlds[cur][(dt * 16 + l15) * 72 + p * 32 + quad * 8];
                #pragma unroll
                for (int it = 0; it < 4; ++it)
                    Oacc[it][dt] = __builtin_amdgcn_mfma_f32_16x16x32_bf16(vf, pfr[it][p].v, Oacc[it][dt], 0, 0, 0);
            }
            __builtin_amdgcn_s_setprio(0);
        };

        // seam-interleaved schedule
        QK(z0, 0, 0);
        QK(z1, 0, 1);                    // covers z0 latency
        EXPPACK(z0, 0, 0);
        EXPPACK(z1, 0, 1);               // pfr[*][0] now complete
        QK(z0, 1, 0);
        PV(0, 0, 2);                     // covers z0(p1a0) latency
        EXPPACK(z0, 1, 0);
        QK(z1, 1, 1);
        PV(0, 2, 5);                     // covers z1(p1a1) latency
        EXPPACK(z1, 1, 1);               // pfr[*][1] now complete
        PV(1, 0, 5);

        // prefetch tile k+2 into regs (overlaps next iter's compute issue)
        if (j0 + 128 < jbase + JCHUNK) {
            const u16* kpj = kp + (size_t)(j0 + 128) * DHEAD;
            pf0 = *(const u16x8*)kpj;
            pf1 = *(const u16x8*)(kpj + 8);
            pf2 = *(const u16x8*)(vp + j0 + 128);
            pf3 = *(const u16x8*)(vp + j0 + 136);
        }
        __syncthreads();                 // ONE barrier per j-step
        cur ^= 1;
    }

    // epilogue: store unnormalized bf16 partial + lsum partial (from MFMA)
    int b = bh >> 3, h = bh & 7;
    u16* opb = op_ws + (size_t)half * 2 * N_POS * INNER;
    float* lwb = lw_ws + (size_t)half * 2 * HEADS * N_POS;
    for (int it = 0; it < 4; ++it) {
        int n = q0 + wv * 64 + it * 16 + l15;
        if (quad == 0) lwb[(size_t)bh * N_POS + n] = Oacc[it][4][0];
        u16* dst = opb + ((size_t)(b * N_POS + n)) * INNER + h * DHEAD;
        for (int dt = 0; dt < 4; ++dt) {
            u16x4 pk;
            for (int r = 0; r < 4; ++r) pk[r] = f2bf(Oacc[it][dt][r]);
            *(u16x4*)&dst[dt * 16 + quad * 4] = pk;
        }
    }
}

// ---------------- K3: combine-once + out-proj + bias (r9-r12-verified) ------
// Block = 16 n-rows x ALL 256 c, 512 threads, grid 512 = 2/CU.  Phase 1: all
// 512 threads combine partials into LDS once.  Phase 2: MFMA loop with
// double-buffered A staging, one barrier per step.  UNCHANGED.
__global__ __launch_bounds__(512) void k3_out(const u16* __restrict__ wo,
                                              const float* __restrict__ b_out,
                                              const u16* __restrict__ op_ws,
                                              const float* __restrict__ lw_ws,
                                              float* __restrict__ out) {
    __shared__ u16 Alds[2][256 * 36];    // [buf][c-row][32 i + 4 pad]
    __shared__ u16 Blds[16 * 520];       // [n-row][512 i + 8 pad]
    int tid = threadIdx.x;
    int n0 = blockIdx.x * 16;
    int b  = blockIdx.y;
    int wv = tid >> 6, l = tid & 63, quad = l >> 4, l15 = l & 15;

    // phase 1: combine 2 bf16 partials -> normalized bf16 B tile in LDS
    {
        int i8 = tid & 63;               // i-chunk of 8 (i = i8*8)
        int h  = i8 >> 3;
        for (int p = 0; p < 2; ++p) {
            int nl = p * 8 + (tid >> 6);
            int n = n0 + nl;
            size_t lidx = ((size_t)(b * HEADS + h)) * N_POS + n;
            float ls = lw_ws[lidx] + lw_ws[(size_t)2 * HEADS * N_POS + lidx];
            float inv = 1.0f / ls;
            size_t oidx = ((size_t)(b * N_POS + n)) * INNER + i8 * 8;
            u16x8 pv0 = *(const u16x8*)(op_ws + oidx);
            u16x8 pv1 = *(const u16x8*)(op_ws + (size_t)2 * N_POS * INNER + oidx);
            u16x8 vv;
            for (int k = 0; k < 8; ++k)
                vv[k] = f2bf((bf2f(pv0[k]) + bf2f(pv1[k])) * inv);
            *(u16x8*)&Blds[nl * 520 + i8 * 8] = vv;
        }
    }
    // stage A for step 0
    {
        int row = tid >> 1, seg = tid & 1;
        const u16* src = wo + (size_t)row * INNER + seg * 16;
        *(u16x8*)&Alds[0][row * 36 + seg * 16]     = *(const u16x8*)src;
        *(u16x8*)&Alds[0][row * 36 + seg * 16 + 8] = *(const u16x8*)(src + 8);
    }
    __syncthreads();

    f32x4 acc[2] = {};                   // [ac] : c = wv*32 + ac*16 + quad*4+r
    int cur = 0;
    for (int s = 0; s < 16; ++s) {
        if (s + 1 < 16) {                // prefetch next A tile (other buffer)
            int row = tid >> 1, seg = tid & 1;
            const u16* src = wo + (size_t)row * INNER + (s + 1) * 32 + seg * 16;
            *(u16x8*)&Alds[cur ^ 1][row * 36 + seg * 16]     = *(const u16x8*)src;
            *(u16x8*)&Alds[cur ^ 1][row * 36 + seg * 16 + 8] = *(const u16x8*)(src + 8);
        }
        for (int ac = 0; ac < 2; ++ac) {
            bf16x8 af = *(const bf16x8*)&Alds[cur][(wv * 32 + ac * 16 + l15) * 36 + quad * 8];
            bf16x8 bfrag = *(const bf16x8*)&Blds[l15 * 520 + s * 32 + quad * 8];
            acc[ac] = __builtin_amdgcn_mfma_f32_16x16x32_bf16(af, bfrag, acc[ac], 0, 0, 0);
        }
        __syncthreads();                 // one barrier per step
        cur ^= 1;
    }
    for (int ac = 0; ac < 2; ++ac)
        for (int r = 0; r < 4; ++r) {
            int c = wv * 32 + ac * 16 + quad * 4 + r;
            out[((size_t)(b * CIN + c)) * N_POS + n0 + l15] = acc[ac][r] + b_out[c];
        }
}

extern "C" void kernel_launch(void* const* d_in, const int* in_sizes, int n_in,
                              void* d_out, int out_size, void* d_ws, size_t ws_size,
                              hipStream_t stream) {
    const float* x     = (const float*)d_in[0];
    const float* w_qkv = (const float*)d_in[1];
    const float* w_out = (const float*)d_in[2];
    const float* b_out = (const float*)d_in[3];
    float* out = (float*)d_out;

    u16* ws    = (u16*)d_ws;
    u16* q_ws  = ws;                                         // 2*8*4096*64 bf16
    u16* k_ws  = q_ws + (size_t)2 * HEADS * N_POS * DHEAD;
    u16* vt_ws = k_ws + (size_t)2 * HEADS * N_POS * DHEAD;
    u16* wo_bf = vt_ws + (size_t)2 * HEADS * N_POS * DHEAD;  // 256*512 bf16
    u16* op_ws = wo_bf + (size_t)CIN * INNER;                // NSPLIT*2*4096*512 bf16
    float* lw_ws = (float*)(op_ws + (size_t)NSPLIT * 2 * N_POS * INNER); // f32

    hipLaunchKernelGGL(k1_qkv, dim3(16, 25, 2), dim3(256), 0, stream,
                       x, w_qkv, w_out, q_ws, k_ws, vt_ws, wo_bf);
    hipLaunchKernelGGL(k2_attn, dim3(16, 16, NSPLIT), dim3(256), 0, stream,
                       q_ws, k_ws, vt_ws, op_ws, lw_ws);
    hipLaunchKernelGGL(k3_out, dim3(256, 2), dim3(512), 0, stream,
                       wo_bf, b_out, op_ws, lw_ws, out);
}